// Round 3
// baseline (535.726 us; speedup 1.0000x reference)
//
#include <hip/hip_runtime.h>

// GraphAE: 2x GCNConv encoder + 2-layer MLP decoder.
// N=50000, IN=128, HID=256, LAT=64, E=800000. All fp32.
//
// R2 changes vs R1:
//  - Layer 1 aggregates BEFORE transform:  (D^-1/2 A^ D^-1/2 X) W1  — halves
//    the gather traffic (512B rows vs 1KB rows). dinv[src] folded into gather.
//  - GEMM rewritten: template tile (BM x BN, TM x TN micro), 128x128 / 8x8 for
//    the wide GEMMs, 128x64 / 8x4 for the N=64 GEMM. FMA:LDS ratio ~2.7:1.
//
// Pipeline (all on `stream`):
//   memset counts=0 ; hist(dst) ; scan1/2/3 -> rowptr ; fill -> col ; dinv
//   AGGX:  xa[i] = dinv[i]*(dinv[i]*x[i] + sum_in dinv[s]*x[s])   [N,128]
//   GEMM1: out1 = relu(xa @ W1 + b1)                              [N,256]
//   GEMM2: zs = (out1 @ W2) * dinv[row]                           [N,64]
//   AGG2:  z  = dinv[i]*(zs[i] + sum_in zs[src]) + b2             [N,64]
//   GEMM3: d  = relu(z @ Wd1 + bd1)                               [N,256]
//   GEMM4: out = d @ Wd2 + bd2                                    [N,128]

#define IN_CH  128
#define HIDDEN 256
#define LATENT 64

static __device__ __forceinline__ float4 ld4(const float* p) {
    return *reinterpret_cast<const float4*>(p);
}
static __device__ __forceinline__ void st4(float* p, float4 v) {
    *reinterpret_cast<float4*>(p) = v;
}
static __device__ __forceinline__ float2 ld2(const float* p) {
    return *reinterpret_cast<const float2*>(p);
}

// ---------------- graph structure kernels ----------------

__global__ void hist_kernel(const int* __restrict__ ei, int E, int* __restrict__ counts) {
    int e = blockIdx.x * 256 + threadIdx.x;
    if (e < E) atomicAdd(&counts[ei[E + e]], 1);
}

__global__ void scan1_kernel(const int* __restrict__ counts, int* __restrict__ rowptr,
                             int* __restrict__ blocksums, int N) {
    __shared__ int sh[256];
    int tid = threadIdx.x;
    int i = blockIdx.x * 256 + tid;
    int v = (i < N) ? counts[i] : 0;
    sh[tid] = v;
    __syncthreads();
    for (int off = 1; off < 256; off <<= 1) {
        int t = (tid >= off) ? sh[tid - off] : 0;
        __syncthreads();
        sh[tid] += t;
        __syncthreads();
    }
    if (i < N) rowptr[i] = sh[tid] - v;
    if (tid == 255) blocksums[blockIdx.x] = sh[255];
}

__global__ void scan2_kernel(const int* __restrict__ blocksums, int* __restrict__ blockoffs,
                             int* __restrict__ rowptr, int nblk, int N) {
    __shared__ int sh[256];
    int tid = threadIdx.x;
    int v = (tid < nblk) ? blocksums[tid] : 0;
    sh[tid] = v;
    __syncthreads();
    for (int off = 1; off < 256; off <<= 1) {
        int t = (tid >= off) ? sh[tid - off] : 0;
        __syncthreads();
        sh[tid] += t;
        __syncthreads();
    }
    if (tid < nblk) blockoffs[tid] = sh[tid] - v;
    if (tid == nblk - 1) rowptr[N] = sh[tid];
}

__global__ void scan3_kernel(int* __restrict__ rowptr, const int* __restrict__ blockoffs,
                             int* __restrict__ next, int N) {
    int i = blockIdx.x * 256 + threadIdx.x;
    if (i < N) {
        int r = rowptr[i] + blockoffs[i >> 8];
        rowptr[i] = r;
        next[i] = r;
    }
}

__global__ void fill_kernel(const int* __restrict__ ei, int E,
                            int* __restrict__ next, int* __restrict__ col) {
    int e = blockIdx.x * 256 + threadIdx.x;
    if (e < E) {
        int s = ei[e];
        int d = ei[E + e];
        int pos = atomicAdd(&next[d], 1);
        col[pos] = s;
    }
}

__global__ void dinv_kernel(const int* __restrict__ counts, float* __restrict__ dinv, int N) {
    int i = blockIdx.x * 256 + threadIdx.x;
    if (i < N) dinv[i] = rsqrtf((float)counts[i] + 1.0f);
}

// ---------------- fp32 tiled GEMM ----------------
// C[M,N] = op(A[M,K] @ B[K,N]); BK=16, 256 threads, TMxTN microtile.
// (BM/TM)*(BN/TN) must equal 256. K % 16 == 0, N % BN == 0 assumed.

template <int BM, int BN, int TM, int TN, bool SCALE_DINV, bool ADD_BIAS, bool RELU>
__global__ __launch_bounds__(256) void gemm_f32(
    const float* __restrict__ A, const float* __restrict__ B, float* __restrict__ C,
    const float* __restrict__ dinv, const float* __restrict__ bias,
    int M, int K, int N) {
    constexpr int BK = 16;
    static_assert((BM / TM) * (BN / TN) == 256, "thread count");
    constexpr int KV4 = BK / 4;              // float4s per A row
    constexpr int A_PER = BM * KV4 / 256;    // float4 loads per thread (A)
    constexpr int B_NV4 = BN / 4;
    constexpr int B_PER = BK * B_NV4 / 256;  // float4 loads per thread (B)

    __shared__ float As[BK][BM + 4];  // [k][m]
    __shared__ float Bs[BK][BN + 4];  // [k][n]

    const int tid = threadIdx.x;
    const int tx = tid % (BN / TN);
    const int ty = tid / (BN / TN);
    const int row0 = blockIdx.x * BM;
    const int n0 = blockIdx.y * BN;

    float acc[TM][TN];
#pragma unroll
    for (int i = 0; i < TM; i++)
#pragma unroll
        for (int j = 0; j < TN; j++) acc[i][j] = 0.0f;

    for (int k0 = 0; k0 < K; k0 += BK) {
        // stage A tile: transpose to [k][m]
#pragma unroll
        for (int j = 0; j < A_PER; j++) {
            int idx = tid + j * 256;
            int m = idx / KV4;
            int kq = (idx % KV4) * 4;
            int row = row0 + m;
            float4 v = make_float4(0.f, 0.f, 0.f, 0.f);
            if (row < M) v = ld4(&A[(long)row * K + k0 + kq]);
            As[kq + 0][m] = v.x;
            As[kq + 1][m] = v.y;
            As[kq + 2][m] = v.z;
            As[kq + 3][m] = v.w;
        }
        // stage B tile
#pragma unroll
        for (int j = 0; j < B_PER; j++) {
            int idx = tid + j * 256;
            int k = idx / B_NV4;
            int n4 = (idx % B_NV4) * 4;
            st4(&Bs[k][n4], ld4(&B[(long)(k0 + k) * N + n0 + n4]));
        }
        __syncthreads();
#pragma unroll
        for (int k = 0; k < BK; k++) {
            float a[TM], b[TN];
#pragma unroll
            for (int i4 = 0; i4 < TM / 4; i4++) {
                float4 v = ld4(&As[k][ty * TM + i4 * 4]);
                a[i4 * 4 + 0] = v.x; a[i4 * 4 + 1] = v.y;
                a[i4 * 4 + 2] = v.z; a[i4 * 4 + 3] = v.w;
            }
#pragma unroll
            for (int j4 = 0; j4 < TN / 4; j4++) {
                float4 v = ld4(&Bs[k][tx * TN + j4 * 4]);
                b[j4 * 4 + 0] = v.x; b[j4 * 4 + 1] = v.y;
                b[j4 * 4 + 2] = v.z; b[j4 * 4 + 3] = v.w;
            }
#pragma unroll
            for (int i = 0; i < TM; i++)
#pragma unroll
                for (int j = 0; j < TN; j++) acc[i][j] += a[i] * b[j];
        }
        __syncthreads();
    }

    // epilogue
#pragma unroll
    for (int i = 0; i < TM; i++) {
        int row = row0 + ty * TM + i;
        if (row >= M) continue;
        float s = SCALE_DINV ? dinv[row] : 1.0f;
#pragma unroll
        for (int j4 = 0; j4 < TN / 4; j4++) {
            int col = n0 + tx * TN + j4 * 4;
            float4 v = make_float4(acc[i][j4 * 4 + 0], acc[i][j4 * 4 + 1],
                                   acc[i][j4 * 4 + 2], acc[i][j4 * 4 + 3]);
            if (SCALE_DINV) { v.x *= s; v.y *= s; v.z *= s; v.w *= s; }
            if (ADD_BIAS) {
                float4 bi = ld4(&bias[col]);
                v.x += bi.x; v.y += bi.y; v.z += bi.z; v.w += bi.w;
            }
            if (RELU) {
                v.x = fmaxf(v.x, 0.f); v.y = fmaxf(v.y, 0.f);
                v.z = fmaxf(v.z, 0.f); v.w = fmaxf(v.w, 0.f);
            }
            st4(&C[(long)row * N + col], v);
        }
    }
}

// ---------------- aggregation kernels ----------------

// AGGX: 128 channels on raw x, dinv[src] folded in. One wave per node,
// lane = 2 channels (float2 -> 512B contiguous per wave access).
__global__ __launch_bounds__(256) void aggx_kernel(
    const float* __restrict__ x, const int* __restrict__ rowptr, const int* __restrict__ col,
    const float* __restrict__ dinv, float* __restrict__ xa, int N) {
    int wave = threadIdx.x >> 6;
    int lane = threadIdx.x & 63;
    int node = blockIdx.x * 4 + wave;
    if (node >= N) return;
    int c = lane * 2;
    float di = dinv[node];
    float2 self = ld2(&x[(long)node * 128 + c]);
    float ax = di * self.x;
    float ay = di * self.y;
    int beg = rowptr[node];
    int end = rowptr[node + 1];
    for (int e = beg; e < end; e++) {
        int s = col[e];
        float ds = dinv[s];
        float2 v = ld2(&x[(long)s * 128 + c]);
        ax += ds * v.x;
        ay += ds * v.y;
    }
    float2 r;
    r.x = di * ax;
    r.y = di * ay;
    *reinterpret_cast<float2*>(&xa[(long)node * 128 + c]) = r;
}

// AGG2: 64 channels. One wave per node; lane = channel.
__global__ __launch_bounds__(256) void agg64_kernel(
    const float* __restrict__ zs, const int* __restrict__ rowptr, const int* __restrict__ col,
    const float* __restrict__ dinv, const float* __restrict__ bias,
    float* __restrict__ out, int N) {
    int wave = threadIdx.x >> 6;
    int lane = threadIdx.x & 63;
    int node = blockIdx.x * 4 + wave;
    if (node >= N) return;
    float acc = zs[(long)node * 64 + lane];
    int beg = rowptr[node];
    int end = rowptr[node + 1];
    for (int e = beg; e < end; e++) {
        acc += zs[(long)col[e] * 64 + lane];
    }
    out[(long)node * 64 + lane] = acc * dinv[node] + bias[lane];
}

// ---------------- launch ----------------

extern "C" void kernel_launch(void* const* d_in, const int* in_sizes, int n_in,
                              void* d_out, int out_size, void* d_ws, size_t ws_size,
                              hipStream_t stream) {
    const float* x        = (const float*)d_in[0];
    const int* ei         = (const int*)d_in[1];   // int32 (harness integer convention)
    const float* W1       = (const float*)d_in[2];
    const float* b1       = (const float*)d_in[3];
    const float* W2       = (const float*)d_in[4];
    const float* b2       = (const float*)d_in[5];
    const float* Wd1      = (const float*)d_in[6];
    const float* bd1      = (const float*)d_in[7];
    const float* Wd2      = (const float*)d_in[8];
    const float* bd2      = (const float*)d_in[9];
    float* out            = (float*)d_out;

    const int N = in_sizes[0] / IN_CH;   // 50000
    const int E = in_sizes[1] / 2;       // 800000

    char* p = (char*)d_ws;
    auto alloc = [&](size_t bytes) {
        char* r = p;
        p += (bytes + 255) & ~(size_t)255;
        return r;
    };
    int*   counts    = (int*)  alloc((size_t)(N + 1) * 4);
    int*   rowptr    = (int*)  alloc((size_t)(N + 1) * 4);
    int*   nxt       = (int*)  alloc((size_t)N * 4);
    int*   blocksums = (int*)  alloc(256 * 4);
    int*   blockoffs = (int*)  alloc(256 * 4);
    float* dinv      = (float*)alloc((size_t)N * 4);
    int*   col       = (int*)  alloc((size_t)E * 4);
    float* xa        = (float*)alloc((size_t)N * IN_CH * 4);
    float* out1      = (float*)alloc((size_t)N * HIDDEN * 4);
    float* zs        = (float*)alloc((size_t)N * LATENT * 4);
    float* z         = (float*)alloc((size_t)N * LATENT * 4);
    float* d         = xa;  // xa dead after GEMM1; GEMM3 output is [N,256]... need space!

    // xa is [N,128] but d is [N,256]; give d its own buffer instead.
    float* dbuf      = (float*)alloc((size_t)N * HIDDEN * 4);
    d = dbuf;

    const int nblk = (N + 255) / 256;

    hipMemsetAsync(counts, 0, (size_t)(N + 1) * 4, stream);
    hist_kernel<<<(E + 255) / 256, 256, 0, stream>>>(ei, E, counts);
    scan1_kernel<<<nblk, 256, 0, stream>>>(counts, rowptr, blocksums, N);
    scan2_kernel<<<1, 256, 0, stream>>>(blocksums, blockoffs, rowptr, nblk, N);
    scan3_kernel<<<nblk, 256, 0, stream>>>(rowptr, blockoffs, nxt, N);
    fill_kernel<<<(E + 255) / 256, 256, 0, stream>>>(ei, E, nxt, col);
    dinv_kernel<<<nblk, 256, 0, stream>>>(counts, dinv, N);

    const int mblk128 = (N + 127) / 128;  // 391

    // AGGX: xa = D^-1/2 A^ D^-1/2 X   [N,128]
    aggx_kernel<<<(N + 3) / 4, 256, 0, stream>>>(x, rowptr, col, dinv, xa, N);
    // GEMM1: out1 = relu(xa @ W1 + b1)   [N,128]x[128,256]
    gemm_f32<128, 128, 8, 8, false, true, true><<<dim3(mblk128, HIDDEN / 128), 256, 0, stream>>>(
        xa, W1, out1, nullptr, b1, N, IN_CH, HIDDEN);
    // GEMM2: zs = (out1 @ W2) * dinv[row]  [N,256]x[256,64]
    gemm_f32<128, 64, 8, 4, true, false, false><<<dim3(mblk128, LATENT / 64), 256, 0, stream>>>(
        out1, W2, zs, dinv, nullptr, N, HIDDEN, LATENT);
    // AGG2: z = dinv*(sum) + b2
    agg64_kernel<<<(N + 3) / 4, 256, 0, stream>>>(zs, rowptr, col, dinv, b2, z, N);
    // GEMM3: d = relu(z @ Wd1 + bd1)   [N,64]x[64,256]
    gemm_f32<128, 128, 8, 8, false, true, true><<<dim3(mblk128, HIDDEN / 128), 256, 0, stream>>>(
        z, Wd1, d, nullptr, bd1, N, LATENT, HIDDEN);
    // GEMM4: out = d @ Wd2 + bd2      [N,256]x[256,128]
    gemm_f32<128, 128, 8, 8, false, true, false><<<dim3(mblk128, IN_CH / 128), 256, 0, stream>>>(
        d, Wd2, out, nullptr, bd2, N, HIDDEN, IN_CH);
}

// Round 4
// 458.074 us; speedup vs baseline: 1.1695x; 1.1695x over previous
//
#include <hip/hip_runtime.h>

// GraphAE: 2x GCNConv encoder + 2-layer MLP decoder.
// N=50000, IN=128, HID=256, LAT=64, E=800000. All fp32.
//
// R4 changes vs R3:
//  - Gathers: prescale xs = dinv*x (kills per-edge dinv load); col indices
//    preloaded 64-at-a-time and broadcast via __shfl (uniform trip count);
//    multi-slot waves (aggx: 2x32-lane float4, agg64: 4x16-lane float4) for
//    2-4x memory-level parallelism. Per-edge VMEM ops: 3 -> ~1.
//  - GEMM micro-tile reads split into two float4 groups at tx*4 / tx*4+64
//    (stride-4, 2-way = free) instead of tx*8 (stride-8, 4-way conflict).

#define IN_CH  128
#define HIDDEN 256
#define LATENT 64

static __device__ __forceinline__ float4 ld4(const float* p) {
    return *reinterpret_cast<const float4*>(p);
}
static __device__ __forceinline__ void st4(float* p, float4 v) {
    *reinterpret_cast<float4*>(p) = v;
}

// ---------------- graph structure kernels ----------------

__global__ void hist_kernel(const int* __restrict__ ei, int E, int* __restrict__ counts) {
    int e = blockIdx.x * 256 + threadIdx.x;
    if (e < E) atomicAdd(&counts[ei[E + e]], 1);
}

__global__ void scan1_kernel(const int* __restrict__ counts, int* __restrict__ rowptr,
                             int* __restrict__ blocksums, int N) {
    __shared__ int sh[256];
    int tid = threadIdx.x;
    int i = blockIdx.x * 256 + tid;
    int v = (i < N) ? counts[i] : 0;
    sh[tid] = v;
    __syncthreads();
    for (int off = 1; off < 256; off <<= 1) {
        int t = (tid >= off) ? sh[tid - off] : 0;
        __syncthreads();
        sh[tid] += t;
        __syncthreads();
    }
    if (i < N) rowptr[i] = sh[tid] - v;
    if (tid == 255) blocksums[blockIdx.x] = sh[255];
}

__global__ void scan2_kernel(const int* __restrict__ blocksums, int* __restrict__ blockoffs,
                             int* __restrict__ rowptr, int nblk, int N) {
    __shared__ int sh[256];
    int tid = threadIdx.x;
    int v = (tid < nblk) ? blocksums[tid] : 0;
    sh[tid] = v;
    __syncthreads();
    for (int off = 1; off < 256; off <<= 1) {
        int t = (tid >= off) ? sh[tid - off] : 0;
        __syncthreads();
        sh[tid] += t;
        __syncthreads();
    }
    if (tid < nblk) blockoffs[tid] = sh[tid] - v;
    if (tid == nblk - 1) rowptr[N] = sh[tid];
}

__global__ void scan3_kernel(int* __restrict__ rowptr, const int* __restrict__ blockoffs,
                             int* __restrict__ next, int N) {
    int i = blockIdx.x * 256 + threadIdx.x;
    if (i < N) {
        int r = rowptr[i] + blockoffs[i >> 8];
        rowptr[i] = r;
        next[i] = r;
    }
}

__global__ void fill_kernel(const int* __restrict__ ei, int E,
                            int* __restrict__ next, int* __restrict__ col) {
    int e = blockIdx.x * 256 + threadIdx.x;
    if (e < E) {
        int s = ei[e];
        int d = ei[E + e];
        int pos = atomicAdd(&next[d], 1);
        col[pos] = s;
    }
}

__global__ void dinv_kernel(const int* __restrict__ counts, float* __restrict__ dinv, int N) {
    int i = blockIdx.x * 256 + threadIdx.x;
    if (i < N) dinv[i] = rsqrtf((float)counts[i] + 1.0f);
}

// xs[i,:] = dinv[i] * x[i,:]  (float4 per thread; 32 float4 per row)
__global__ void prescale_kernel(const float* __restrict__ x, const float* __restrict__ dinv,
                                float* __restrict__ xs, int total4) {
    int i = blockIdx.x * 256 + threadIdx.x;
    if (i < total4) {
        float s = dinv[i >> 5];
        float4 v = ld4(&x[(long)i * 4]);
        v.x *= s; v.y *= s; v.z *= s; v.w *= s;
        st4(&xs[(long)i * 4], v);
    }
}

// ---------------- fp32 tiled GEMM ----------------
// C[M,N] = op(A @ B); BK=16, 256 threads, TM x TN microtile split into
// 4-wide groups: rows ty*4 + g*RS, cols tx*4 + h*CS  (RS=(BM/TM)*4, CS=(BN/TN)*4).

template <int BM, int BN, int TM, int TN, bool SCALE_DINV, bool ADD_BIAS, bool RELU>
__global__ __launch_bounds__(256) void gemm_f32(
    const float* __restrict__ A, const float* __restrict__ B, float* __restrict__ C,
    const float* __restrict__ dinv, const float* __restrict__ bias,
    int M, int K, int N) {
    constexpr int BK = 16;
    static_assert((BM / TM) * (BN / TN) == 256, "thread count");
    constexpr int MG = TM / 4;            // row groups
    constexpr int NG = TN / 4;            // col groups
    constexpr int RS = (BM / TM) * 4;     // row group stride
    constexpr int CS = (BN / TN) * 4;     // col group stride
    constexpr int KV4 = BK / 4;
    constexpr int A_PER = BM * KV4 / 256;
    constexpr int B_NV4 = BN / 4;
    constexpr int B_PER = BK * B_NV4 / 256;

    __shared__ float As[BK][BM + 4];
    __shared__ float Bs[BK][BN + 4];

    const int tid = threadIdx.x;
    const int tx = tid % (BN / TN);
    const int ty = tid / (BN / TN);
    const int row0 = blockIdx.x * BM;
    const int n0 = blockIdx.y * BN;

    float acc[TM][TN];
#pragma unroll
    for (int i = 0; i < TM; i++)
#pragma unroll
        for (int j = 0; j < TN; j++) acc[i][j] = 0.0f;

    for (int k0 = 0; k0 < K; k0 += BK) {
#pragma unroll
        for (int j = 0; j < A_PER; j++) {
            int idx = tid + j * 256;
            int m = idx / KV4;
            int kq = (idx % KV4) * 4;
            int row = row0 + m;
            float4 v = make_float4(0.f, 0.f, 0.f, 0.f);
            if (row < M) v = ld4(&A[(long)row * K + k0 + kq]);
            As[kq + 0][m] = v.x;
            As[kq + 1][m] = v.y;
            As[kq + 2][m] = v.z;
            As[kq + 3][m] = v.w;
        }
#pragma unroll
        for (int j = 0; j < B_PER; j++) {
            int idx = tid + j * 256;
            int k = idx / B_NV4;
            int n4 = (idx % B_NV4) * 4;
            st4(&Bs[k][n4], ld4(&B[(long)(k0 + k) * N + n0 + n4]));
        }
        __syncthreads();
#pragma unroll
        for (int k = 0; k < BK; k++) {
            float a[TM], b[TN];
#pragma unroll
            for (int g = 0; g < MG; g++) {
                float4 v = ld4(&As[k][ty * 4 + g * RS]);
                a[g * 4 + 0] = v.x; a[g * 4 + 1] = v.y;
                a[g * 4 + 2] = v.z; a[g * 4 + 3] = v.w;
            }
#pragma unroll
            for (int h = 0; h < NG; h++) {
                float4 v = ld4(&Bs[k][tx * 4 + h * CS]);
                b[h * 4 + 0] = v.x; b[h * 4 + 1] = v.y;
                b[h * 4 + 2] = v.z; b[h * 4 + 3] = v.w;
            }
#pragma unroll
            for (int i = 0; i < TM; i++)
#pragma unroll
                for (int j = 0; j < TN; j++) acc[i][j] += a[i] * b[j];
        }
        __syncthreads();
    }

#pragma unroll
    for (int g = 0; g < MG; g++)
#pragma unroll
        for (int i = 0; i < 4; i++) {
            int row = row0 + ty * 4 + g * RS + i;
            if (row >= M) continue;
            float s = SCALE_DINV ? dinv[row] : 1.0f;
#pragma unroll
            for (int h = 0; h < NG; h++) {
                int colc = n0 + tx * 4 + h * CS;
                float4 v = make_float4(acc[g * 4 + i][h * 4 + 0], acc[g * 4 + i][h * 4 + 1],
                                       acc[g * 4 + i][h * 4 + 2], acc[g * 4 + i][h * 4 + 3]);
                if (SCALE_DINV) { v.x *= s; v.y *= s; v.z *= s; v.w *= s; }
                if (ADD_BIAS) {
                    float4 bi = ld4(&bias[colc]);
                    v.x += bi.x; v.y += bi.y; v.z += bi.z; v.w += bi.w;
                }
                if (RELU) {
                    v.x = fmaxf(v.x, 0.f); v.y = fmaxf(v.y, 0.f);
                    v.z = fmaxf(v.z, 0.f); v.w = fmaxf(v.w, 0.f);
                }
                st4(&C[(long)row * N + colc], v);
            }
        }
}

// ---------------- aggregation kernels ----------------

// AGGX: xa[i] = dinv[i] * (xs[i] + sum_in xs[s]), xs already dinv-prescaled.
// One wave per node, 2 slots x 32 lanes x float4 (512B/row). col preloaded
// 64-at-a-time, broadcast via shfl with uniform trip count.
__global__ __launch_bounds__(256) void aggx_kernel(
    const float* __restrict__ xs, const int* __restrict__ rowptr, const int* __restrict__ col,
    const float* __restrict__ dinv, float* __restrict__ xa, int N) {
    int wid = threadIdx.x >> 6;
    int lane = threadIdx.x & 63;
    int node = blockIdx.x * 4 + wid;
    if (node >= N) return;
    int slot = lane >> 5;
    int c = (lane & 31) * 4;

    float4 acc = make_float4(0.f, 0.f, 0.f, 0.f);
    if (slot == 0) acc = ld4(&xs[(long)node * 128 + c]);  // self term

    int beg = rowptr[node];
    int end = rowptr[node + 1];
    for (int cb = beg; cb < end; cb += 64) {
        int cnt = min(64, end - cb);
        int cv = (lane < cnt) ? col[cb + lane] : 0;
        int trips = (cnt + 1) >> 1;
        for (int t = 0; t < trips; t++) {
            int j = slot + 2 * t;
            bool p = j < cnt;
            int s = __shfl(cv, p ? j : 0);
            if (p) {
                float4 v = ld4(&xs[(long)s * 128 + c]);
                acc.x += v.x; acc.y += v.y; acc.z += v.z; acc.w += v.w;
            }
        }
    }
    acc.x += __shfl_xor(acc.x, 32);
    acc.y += __shfl_xor(acc.y, 32);
    acc.z += __shfl_xor(acc.z, 32);
    acc.w += __shfl_xor(acc.w, 32);
    if (slot == 0) {
        float di = dinv[node];
        acc.x *= di; acc.y *= di; acc.z *= di; acc.w *= di;
        st4(&xa[(long)node * 128 + c], acc);
    }
}

// AGG2: z[i] = dinv[i]*(zs[i] + sum_in zs[s]) + b2; zs already dinv[src]-scaled.
// One wave per node, 4 slots x 16 lanes x float4 (256B/row).
__global__ __launch_bounds__(256) void agg64_kernel(
    const float* __restrict__ zs, const int* __restrict__ rowptr, const int* __restrict__ col,
    const float* __restrict__ dinv, const float* __restrict__ bias,
    float* __restrict__ out, int N) {
    int wid = threadIdx.x >> 6;
    int lane = threadIdx.x & 63;
    int node = blockIdx.x * 4 + wid;
    if (node >= N) return;
    int slot = lane >> 4;
    int c = (lane & 15) * 4;

    float4 acc = make_float4(0.f, 0.f, 0.f, 0.f);
    if (slot == 0) acc = ld4(&zs[(long)node * 64 + c]);  // self term

    int beg = rowptr[node];
    int end = rowptr[node + 1];
    for (int cb = beg; cb < end; cb += 64) {
        int cnt = min(64, end - cb);
        int cv = (lane < cnt) ? col[cb + lane] : 0;
        int trips = (cnt + 3) >> 2;
        for (int t = 0; t < trips; t++) {
            int j = slot + 4 * t;
            bool p = j < cnt;
            int s = __shfl(cv, p ? j : 0);
            if (p) {
                float4 v = ld4(&zs[(long)s * 64 + c]);
                acc.x += v.x; acc.y += v.y; acc.z += v.z; acc.w += v.w;
            }
        }
    }
    acc.x += __shfl_xor(acc.x, 16); acc.x += __shfl_xor(acc.x, 32);
    acc.y += __shfl_xor(acc.y, 16); acc.y += __shfl_xor(acc.y, 32);
    acc.z += __shfl_xor(acc.z, 16); acc.z += __shfl_xor(acc.z, 32);
    acc.w += __shfl_xor(acc.w, 16); acc.w += __shfl_xor(acc.w, 32);
    if (slot == 0) {
        float di = dinv[node];
        float4 bi = ld4(&bias[c]);
        acc.x = acc.x * di + bi.x;
        acc.y = acc.y * di + bi.y;
        acc.z = acc.z * di + bi.z;
        acc.w = acc.w * di + bi.w;
        st4(&out[(long)node * 64 + c], acc);
    }
}

// ---------------- launch ----------------

extern "C" void kernel_launch(void* const* d_in, const int* in_sizes, int n_in,
                              void* d_out, int out_size, void* d_ws, size_t ws_size,
                              hipStream_t stream) {
    const float* x        = (const float*)d_in[0];
    const int* ei         = (const int*)d_in[1];   // int32 (harness integer convention)
    const float* W1       = (const float*)d_in[2];
    const float* b1       = (const float*)d_in[3];
    const float* W2       = (const float*)d_in[4];
    const float* b2       = (const float*)d_in[5];
    const float* Wd1      = (const float*)d_in[6];
    const float* bd1      = (const float*)d_in[7];
    const float* Wd2      = (const float*)d_in[8];
    const float* bd2      = (const float*)d_in[9];
    float* out            = (float*)d_out;

    const int N = in_sizes[0] / IN_CH;   // 50000
    const int E = in_sizes[1] / 2;       // 800000

    char* p = (char*)d_ws;
    auto alloc = [&](size_t bytes) {
        char* r = p;
        p += (bytes + 255) & ~(size_t)255;
        return r;
    };
    int*   counts    = (int*)  alloc((size_t)(N + 1) * 4);
    int*   rowptr    = (int*)  alloc((size_t)(N + 1) * 4);
    int*   nxt       = (int*)  alloc((size_t)N * 4);
    int*   blocksums = (int*)  alloc(256 * 4);
    int*   blockoffs = (int*)  alloc(256 * 4);
    float* dinv      = (float*)alloc((size_t)N * 4);
    int*   col       = (int*)  alloc((size_t)E * 4);
    float* xs        = (float*)alloc((size_t)N * IN_CH * 4);   // dinv-prescaled x
    float* xa        = (float*)alloc((size_t)N * IN_CH * 4);   // aggregated input
    float* out1      = (float*)alloc((size_t)N * HIDDEN * 4);
    float* zs        = (float*)alloc((size_t)N * LATENT * 4);
    float* z         = (float*)alloc((size_t)N * LATENT * 4);
    // xs & xa (adjacent, 2*N*128 floats = N*256) are dead after GEMM1 -> reuse as d
    float* d         = xs;

    const int nblk = (N + 255) / 256;

    hipMemsetAsync(counts, 0, (size_t)(N + 1) * 4, stream);
    hist_kernel<<<(E + 255) / 256, 256, 0, stream>>>(ei, E, counts);
    scan1_kernel<<<nblk, 256, 0, stream>>>(counts, rowptr, blocksums, N);
    scan2_kernel<<<1, 256, 0, stream>>>(blocksums, blockoffs, rowptr, nblk, N);
    scan3_kernel<<<nblk, 256, 0, stream>>>(rowptr, blockoffs, nxt, N);
    fill_kernel<<<(E + 255) / 256, 256, 0, stream>>>(ei, E, nxt, col);
    dinv_kernel<<<nblk, 256, 0, stream>>>(counts, dinv, N);

    const int total4 = N * (IN_CH / 4);
    prescale_kernel<<<(total4 + 255) / 256, 256, 0, stream>>>(x, dinv, xs, total4);

    const int mblk128 = (N + 127) / 128;  // 391

    // AGGX: xa = D^-1/2 A^ D^-1/2 X   [N,128]
    aggx_kernel<<<(N + 3) / 4, 256, 0, stream>>>(xs, rowptr, col, dinv, xa, N);
    // GEMM1: out1 = relu(xa @ W1 + b1)   [N,128]x[128,256]
    gemm_f32<128, 128, 8, 8, false, true, true><<<dim3(mblk128, HIDDEN / 128), 256, 0, stream>>>(
        xa, W1, out1, nullptr, b1, N, IN_CH, HIDDEN);
    // GEMM2: zs = (out1 @ W2) * dinv[row]  [N,256]x[256,64]
    gemm_f32<128, 64, 8, 4, true, false, false><<<dim3(mblk128, LATENT / 64), 256, 0, stream>>>(
        out1, W2, zs, dinv, nullptr, N, HIDDEN, LATENT);
    // AGG2: z = dinv*(sum) + b2
    agg64_kernel<<<(N + 3) / 4, 256, 0, stream>>>(zs, rowptr, col, dinv, b2, z, N);
    // GEMM3: d = relu(z @ Wd1 + bd1)   [N,64]x[64,256]
    gemm_f32<128, 128, 8, 8, false, true, true><<<dim3(mblk128, HIDDEN / 128), 256, 0, stream>>>(
        z, Wd1, d, nullptr, bd1, N, LATENT, HIDDEN);
    // GEMM4: out = d @ Wd2 + bd2      [N,256]x[256,128]
    gemm_f32<128, 128, 8, 8, false, true, false><<<dim3(mblk128, IN_CH / 128), 256, 0, stream>>>(
        d, Wd2, out, nullptr, bd2, N, HIDDEN, IN_CH);
}

// Round 5
// 397.130 us; speedup vs baseline: 1.3490x; 1.1535x over previous
//
#include <hip/hip_runtime.h>

// GraphAE: 2x GCNConv encoder + 2-layer MLP decoder.
// N=50000, IN=128, HID=256, LAT=64, E=800000. fp32 in/out.
//
// R5: all four GEMMs moved to MFMA via bf16x3 split-precision emulation:
//   v = hi + lo (bf16 planes, truncating split; residual ~2^-16 rel)
//   A@B ~= Ahi@Bhi + Ahi@Blo + Alo@Bhi  (lo*lo dropped, ~2^-18 rel)
// Intermediates (xa, out1, z, d) are produced directly as hi/lo planes by the
// upstream epilogue (no extra conversion passes; same bytes as fp32).
// Weights transposed+split to [N,K] planes so B-frags are K-contiguous.
// MFMA 16x16x32_bf16; A[m=lane&15][k=quad*8+j], B[k=quad*8+j][n=lane&15],
// C/D col=lane&15 row=quad*4+reg (HW-verified mappings).

#define IN_CH  128
#define HIDDEN 256
#define LATENT 64

typedef unsigned short u16;
typedef unsigned int u32;
typedef __bf16 bf16x8 __attribute__((ext_vector_type(8)));
typedef float f32x4 __attribute__((ext_vector_type(4)));

static __device__ __forceinline__ float4 ld4(const float* p) {
    return *reinterpret_cast<const float4*>(p);
}
static __device__ __forceinline__ void st4(float* p, float4 v) {
    *reinterpret_cast<float4*>(p) = v;
}

// truncating hi/lo split: hi = top16(v); lo = top16(v - hi). v-hi is exact.
static __device__ __forceinline__ void split_bf16(float v, u16& hi, u16& lo) {
    u32 b = __float_as_uint(v);
    hi = (u16)(b >> 16);
    float hf = __uint_as_float(b & 0xFFFF0000u);
    lo = (u16)(__float_as_uint(v - hf) >> 16);
}

// ---------------- graph structure kernels ----------------

__global__ void hist_kernel(const int* __restrict__ ei, int E, int* __restrict__ counts) {
    int e = blockIdx.x * 256 + threadIdx.x;
    if (e < E) atomicAdd(&counts[ei[E + e]], 1);
}

__global__ void scan1_kernel(const int* __restrict__ counts, int* __restrict__ rowptr,
                             int* __restrict__ blocksums, int N) {
    __shared__ int sh[256];
    int tid = threadIdx.x;
    int i = blockIdx.x * 256 + tid;
    int v = (i < N) ? counts[i] : 0;
    sh[tid] = v;
    __syncthreads();
    for (int off = 1; off < 256; off <<= 1) {
        int t = (tid >= off) ? sh[tid - off] : 0;
        __syncthreads();
        sh[tid] += t;
        __syncthreads();
    }
    if (i < N) rowptr[i] = sh[tid] - v;
    if (tid == 255) blocksums[blockIdx.x] = sh[255];
}

__global__ void scan2_kernel(const int* __restrict__ blocksums, int* __restrict__ blockoffs,
                             int* __restrict__ rowptr, int nblk, int N) {
    __shared__ int sh[256];
    int tid = threadIdx.x;
    int v = (tid < nblk) ? blocksums[tid] : 0;
    sh[tid] = v;
    __syncthreads();
    for (int off = 1; off < 256; off <<= 1) {
        int t = (tid >= off) ? sh[tid - off] : 0;
        __syncthreads();
        sh[tid] += t;
        __syncthreads();
    }
    if (tid < nblk) blockoffs[tid] = sh[tid] - v;
    if (tid == nblk - 1) rowptr[N] = sh[tid];
}

__global__ void scan3_kernel(int* __restrict__ rowptr, const int* __restrict__ blockoffs,
                             int* __restrict__ next, int N) {
    int i = blockIdx.x * 256 + threadIdx.x;
    if (i < N) {
        int r = rowptr[i] + blockoffs[i >> 8];
        rowptr[i] = r;
        next[i] = r;
    }
}

__global__ void fill_kernel(const int* __restrict__ ei, int E,
                            int* __restrict__ next, int* __restrict__ col) {
    int e = blockIdx.x * 256 + threadIdx.x;
    if (e < E) {
        int s = ei[e];
        int d = ei[E + e];
        int pos = atomicAdd(&next[d], 1);
        col[pos] = s;
    }
}

__global__ void dinv_kernel(const int* __restrict__ counts, float* __restrict__ dinv, int N) {
    int i = blockIdx.x * 256 + threadIdx.x;
    if (i < N) dinv[i] = rsqrtf((float)counts[i] + 1.0f);
}

// xs[i,:] = dinv[i] * x[i,:]
__global__ void prescale_kernel(const float* __restrict__ x, const float* __restrict__ dinv,
                                float* __restrict__ xs, int total4) {
    int i = blockIdx.x * 256 + threadIdx.x;
    if (i < total4) {
        float s = dinv[i >> 5];
        float4 v = ld4(&x[(long)i * 4]);
        v.x *= s; v.y *= s; v.z *= s; v.w *= s;
        st4(&xs[(long)i * 4], v);
    }
}

// W[K,N] fp32 -> Wt_hi/Wt_lo [N,K] bf16 planes
__global__ void wsplit_kernel(const float* __restrict__ W, u16* __restrict__ Whi,
                              u16* __restrict__ Wlo, int K, int N) {
    int idx = blockIdx.x * 256 + threadIdx.x;
    if (idx < K * N) {
        int k = idx / N, n = idx % N;
        u16 h, l;
        split_bf16(W[idx], h, l);
        Whi[(long)n * K + k] = h;
        Wlo[(long)n * K + k] = l;
    }
}

// ---------------- bf16x3 MFMA GEMM ----------------
// C[M,N] = A[M,K] @ B[K,N] in fp32-equivalent precision.
// A given as hi/lo bf16 planes [M,K]; B as hi/lo planes TRANSPOSED [N,K].
// BM=128 rows, BN cols, BK=32, 256 threads = 4 waves in WR x WC grid,
// each wave computes MI x NJ subtiles of 16x16 via mfma_f32_16x16x32_bf16.

template <int BM, int BN, int WR, int WC, bool SPLIT_OUT, bool ADD_BIAS, bool RELU, bool SCALE_DINV>
__global__ __launch_bounds__(256) void gemm_bf16x3(
    const u16* __restrict__ Ahi, const u16* __restrict__ Alo,
    const u16* __restrict__ Bthi, const u16* __restrict__ Btlo,
    float* __restrict__ Cf, u16* __restrict__ Chi, u16* __restrict__ Clo,
    const float* __restrict__ dinv, const float* __restrict__ bias,
    int M, int K, int N) {
    constexpr int BK = 32;
    static_assert(WR * WC == 4, "4 waves");
    constexpr int MI = BM / (WR * 16);
    constexpr int NJ = BN / (WC * 16);
    constexpr int APER = BM * BK / 8 / 256;  // 16B chunks per thread per plane
    constexpr int BPER = BN * BK / 8 / 256;

    __shared__ u16 As[2][BM * BK];  // [plane][m*BK + k]
    __shared__ u16 Bs[2][BN * BK];  // [plane][n*BK + k]

    const int tid = threadIdx.x;
    const int wid = tid >> 6;
    const int lane = tid & 63;
    const int quad = lane >> 4;
    const int lm = lane & 15;
    const int wr = wid / WC;
    const int wc = wid % WC;
    const int row0 = blockIdx.x * BM;
    const int n0 = blockIdx.y * BN;

    f32x4 acc[MI][NJ];
#pragma unroll
    for (int i = 0; i < MI; i++)
#pragma unroll
        for (int j = 0; j < NJ; j++) acc[i][j] = (f32x4){0.f, 0.f, 0.f, 0.f};

    for (int k0 = 0; k0 < K; k0 += BK) {
        // stage A (straight copy, zero-fill OOB rows)
#pragma unroll
        for (int t = 0; t < APER; t++) {
            int idx = tid + t * 256;
            int m = idx >> 2;            // BK/8 = 4 groups of 8 per row
            int kg = (idx & 3) * 8;
            int row = row0 + m;
            uint4 vh = make_uint4(0, 0, 0, 0), vl = make_uint4(0, 0, 0, 0);
            if (row < M) {
                vh = *(const uint4*)&Ahi[(long)row * K + k0 + kg];
                vl = *(const uint4*)&Alo[(long)row * K + k0 + kg];
            }
            *(uint4*)&As[0][m * BK + kg] = vh;
            *(uint4*)&As[1][m * BK + kg] = vl;
        }
        // stage B (N % BN == 0, no guard)
#pragma unroll
        for (int t = 0; t < BPER; t++) {
            int idx = tid + t * 256;
            int n = idx >> 2;
            int kg = (idx & 3) * 8;
            *(uint4*)&Bs[0][n * BK + kg] = *(const uint4*)&Bthi[(long)(n0 + n) * K + k0 + kg];
            *(uint4*)&Bs[1][n * BK + kg] = *(const uint4*)&Btlo[(long)(n0 + n) * K + k0 + kg];
        }
        __syncthreads();

        bf16x8 ah[MI], al[MI], bh[NJ], bl[NJ];
#pragma unroll
        for (int i = 0; i < MI; i++) {
            int m = wr * (MI * 16) + i * 16 + lm;
            ah[i] = *(const bf16x8*)&As[0][m * BK + quad * 8];
            al[i] = *(const bf16x8*)&As[1][m * BK + quad * 8];
        }
#pragma unroll
        for (int j = 0; j < NJ; j++) {
            int n = wc * (NJ * 16) + j * 16 + lm;
            bh[j] = *(const bf16x8*)&Bs[0][n * BK + quad * 8];
            bl[j] = *(const bf16x8*)&Bs[1][n * BK + quad * 8];
        }
#pragma unroll
        for (int i = 0; i < MI; i++)
#pragma unroll
            for (int j = 0; j < NJ; j++) {
                acc[i][j] = __builtin_amdgcn_mfma_f32_16x16x32_bf16(ah[i], bh[j], acc[i][j], 0, 0, 0);
                acc[i][j] = __builtin_amdgcn_mfma_f32_16x16x32_bf16(ah[i], bl[j], acc[i][j], 0, 0, 0);
                acc[i][j] = __builtin_amdgcn_mfma_f32_16x16x32_bf16(al[i], bh[j], acc[i][j], 0, 0, 0);
            }
        __syncthreads();
    }

    // epilogue: C/D mapping col=lane&15 (N), row=quad*4+reg (M)
#pragma unroll
    for (int i = 0; i < MI; i++)
#pragma unroll
        for (int j = 0; j < NJ; j++) {
            int coln = n0 + wc * (NJ * 16) + j * 16 + lm;
            float bi = ADD_BIAS ? bias[coln] : 0.0f;
#pragma unroll
            for (int r = 0; r < 4; r++) {
                int row = row0 + wr * (MI * 16) + i * 16 + quad * 4 + r;
                if (row < M) {
                    float v = acc[i][j][r];
                    if (SCALE_DINV) v *= dinv[row];
                    if (ADD_BIAS) v += bi;
                    if (RELU) v = fmaxf(v, 0.f);
                    if (SPLIT_OUT) {
                        u16 h, l;
                        split_bf16(v, h, l);
                        Chi[(long)row * N + coln] = h;
                        Clo[(long)row * N + coln] = l;
                    } else {
                        Cf[(long)row * N + coln] = v;
                    }
                }
            }
        }
}

// ---------------- aggregation kernels ----------------

// AGGX: xa[i] = dinv[i]*(xs[i] + sum_in xs[s]); writes SPLIT hi/lo planes.
// One wave per node, 2 slots x 32 lanes x float4. col broadcast via shfl.
__global__ __launch_bounds__(256) void aggx_kernel(
    const float* __restrict__ xs, const int* __restrict__ rowptr, const int* __restrict__ col,
    const float* __restrict__ dinv, u16* __restrict__ xahi, u16* __restrict__ xalo, int N) {
    int wid = threadIdx.x >> 6;
    int lane = threadIdx.x & 63;
    int node = blockIdx.x * 4 + wid;
    if (node >= N) return;
    int slot = lane >> 5;
    int c = (lane & 31) * 4;

    float4 acc = make_float4(0.f, 0.f, 0.f, 0.f);
    if (slot == 0) acc = ld4(&xs[(long)node * 128 + c]);  // self term

    int beg = rowptr[node];
    int end = rowptr[node + 1];
    for (int cb = beg; cb < end; cb += 64) {
        int cnt = min(64, end - cb);
        int cv = (lane < cnt) ? col[cb + lane] : 0;
        int trips = (cnt + 1) >> 1;
        for (int t = 0; t < trips; t++) {
            int j = slot + 2 * t;
            bool p = j < cnt;
            int s = __shfl(cv, p ? j : 0);
            if (p) {
                float4 v = ld4(&xs[(long)s * 128 + c]);
                acc.x += v.x; acc.y += v.y; acc.z += v.z; acc.w += v.w;
            }
        }
    }
    acc.x += __shfl_xor(acc.x, 32);
    acc.y += __shfl_xor(acc.y, 32);
    acc.z += __shfl_xor(acc.z, 32);
    acc.w += __shfl_xor(acc.w, 32);
    if (slot == 0) {
        float di = dinv[node];
        acc.x *= di; acc.y *= di; acc.z *= di; acc.w *= di;
        ushort4 h, l;
        split_bf16(acc.x, h.x, l.x);
        split_bf16(acc.y, h.y, l.y);
        split_bf16(acc.z, h.z, l.z);
        split_bf16(acc.w, h.w, l.w);
        *(ushort4*)&xahi[(long)node * 128 + c] = h;
        *(ushort4*)&xalo[(long)node * 128 + c] = l;
    }
}

// AGG2: z[i] = dinv[i]*(zs[i] + sum_in zs[s]) + b2; writes SPLIT hi/lo planes.
// One wave per node, 4 slots x 16 lanes x float4.
__global__ __launch_bounds__(256) void agg64_kernel(
    const float* __restrict__ zs, const int* __restrict__ rowptr, const int* __restrict__ col,
    const float* __restrict__ dinv, const float* __restrict__ bias,
    u16* __restrict__ zhi, u16* __restrict__ zlo, int N) {
    int wid = threadIdx.x >> 6;
    int lane = threadIdx.x & 63;
    int node = blockIdx.x * 4 + wid;
    if (node >= N) return;
    int slot = lane >> 4;
    int c = (lane & 15) * 4;

    float4 acc = make_float4(0.f, 0.f, 0.f, 0.f);
    if (slot == 0) acc = ld4(&zs[(long)node * 64 + c]);  // self term

    int beg = rowptr[node];
    int end = rowptr[node + 1];
    for (int cb = beg; cb < end; cb += 64) {
        int cnt = min(64, end - cb);
        int cv = (lane < cnt) ? col[cb + lane] : 0;
        int trips = (cnt + 3) >> 2;
        for (int t = 0; t < trips; t++) {
            int j = slot + 4 * t;
            bool p = j < cnt;
            int s = __shfl(cv, p ? j : 0);
            if (p) {
                float4 v = ld4(&zs[(long)s * 64 + c]);
                acc.x += v.x; acc.y += v.y; acc.z += v.z; acc.w += v.w;
            }
        }
    }
    acc.x += __shfl_xor(acc.x, 16); acc.x += __shfl_xor(acc.x, 32);
    acc.y += __shfl_xor(acc.y, 16); acc.y += __shfl_xor(acc.y, 32);
    acc.z += __shfl_xor(acc.z, 16); acc.z += __shfl_xor(acc.z, 32);
    acc.w += __shfl_xor(acc.w, 16); acc.w += __shfl_xor(acc.w, 32);
    if (slot == 0) {
        float di = dinv[node];
        float4 bi = ld4(&bias[c]);
        acc.x = acc.x * di + bi.x;
        acc.y = acc.y * di + bi.y;
        acc.z = acc.z * di + bi.z;
        acc.w = acc.w * di + bi.w;
        ushort4 h, l;
        split_bf16(acc.x, h.x, l.x);
        split_bf16(acc.y, h.y, l.y);
        split_bf16(acc.z, h.z, l.z);
        split_bf16(acc.w, h.w, l.w);
        *(ushort4*)&zhi[(long)node * 64 + c] = h;
        *(ushort4*)&zlo[(long)node * 64 + c] = l;
    }
}

// ---------------- launch ----------------

extern "C" void kernel_launch(void* const* d_in, const int* in_sizes, int n_in,
                              void* d_out, int out_size, void* d_ws, size_t ws_size,
                              hipStream_t stream) {
    const float* x        = (const float*)d_in[0];
    const int* ei         = (const int*)d_in[1];   // int32 (harness integer convention)
    const float* W1       = (const float*)d_in[2];
    const float* b1       = (const float*)d_in[3];
    const float* W2       = (const float*)d_in[4];
    const float* b2       = (const float*)d_in[5];
    const float* Wd1      = (const float*)d_in[6];
    const float* bd1      = (const float*)d_in[7];
    const float* Wd2      = (const float*)d_in[8];
    const float* bd2      = (const float*)d_in[9];
    float* out            = (float*)d_out;

    const int N = in_sizes[0] / IN_CH;   // 50000
    const int E = in_sizes[1] / 2;       // 800000

    char* p = (char*)d_ws;
    auto alloc = [&](size_t bytes) {
        char* r = p;
        p += (bytes + 255) & ~(size_t)255;
        return r;
    };
    int*   counts    = (int*)  alloc((size_t)(N + 1) * 4);
    int*   rowptr    = (int*)  alloc((size_t)(N + 1) * 4);
    int*   nxt       = (int*)  alloc((size_t)N * 4);
    int*   blocksums = (int*)  alloc(256 * 4);
    int*   blockoffs = (int*)  alloc(256 * 4);
    float* dinv      = (float*)alloc((size_t)N * 4);
    int*   col       = (int*)  alloc((size_t)E * 4);
    float* xs        = (float*)alloc((size_t)N * IN_CH * 4);      // fp32; reused as d_hi
    u16*   blk2      = (u16*)  alloc((size_t)N * HIDDEN * 2);     // xa_hi|xa_lo; reused as d_lo
    u16*   out1_hi   = (u16*)  alloc((size_t)N * HIDDEN * 2);
    u16*   out1_lo   = (u16*)  alloc((size_t)N * HIDDEN * 2);
    float* zs        = (float*)alloc((size_t)N * LATENT * 4);
    u16*   z_hi      = (u16*)  alloc((size_t)N * LATENT * 2);
    u16*   z_lo      = (u16*)  alloc((size_t)N * LATENT * 2);
    u16*   w1t_hi    = (u16*)  alloc((size_t)IN_CH * HIDDEN * 2);
    u16*   w1t_lo    = (u16*)  alloc((size_t)IN_CH * HIDDEN * 2);
    u16*   w2t_hi    = (u16*)  alloc((size_t)HIDDEN * LATENT * 2);
    u16*   w2t_lo    = (u16*)  alloc((size_t)HIDDEN * LATENT * 2);
    u16*   wd1t_hi   = (u16*)  alloc((size_t)LATENT * HIDDEN * 2);
    u16*   wd1t_lo   = (u16*)  alloc((size_t)LATENT * HIDDEN * 2);
    u16*   wd2t_hi   = (u16*)  alloc((size_t)HIDDEN * IN_CH * 2);
    u16*   wd2t_lo   = (u16*)  alloc((size_t)HIDDEN * IN_CH * 2);

    u16* xa_hi = blk2;
    u16* xa_lo = blk2 + (size_t)N * IN_CH;
    // d [N,256] split: reuse xs (25.6MB -> d_hi) and blk2 (25.6MB -> d_lo);
    // xs dead after aggx, xa dead after GEMM1, both before GEMM3 writes d.
    u16* d_hi = (u16*)xs;
    u16* d_lo = blk2;

    const int nblk = (N + 255) / 256;

    hipMemsetAsync(counts, 0, (size_t)(N + 1) * 4, stream);
    hist_kernel<<<(E + 255) / 256, 256, 0, stream>>>(ei, E, counts);
    scan1_kernel<<<nblk, 256, 0, stream>>>(counts, rowptr, blocksums, N);
    scan2_kernel<<<1, 256, 0, stream>>>(blocksums, blockoffs, rowptr, nblk, N);
    scan3_kernel<<<nblk, 256, 0, stream>>>(rowptr, blockoffs, nxt, N);
    fill_kernel<<<(E + 255) / 256, 256, 0, stream>>>(ei, E, nxt, col);
    dinv_kernel<<<nblk, 256, 0, stream>>>(counts, dinv, N);

    const int total4 = N * (IN_CH / 4);
    prescale_kernel<<<(total4 + 255) / 256, 256, 0, stream>>>(x, dinv, xs, total4);

    // weight transpose+split (tiny)
    wsplit_kernel<<<(IN_CH * HIDDEN + 255) / 256, 256, 0, stream>>>(W1, w1t_hi, w1t_lo, IN_CH, HIDDEN);
    wsplit_kernel<<<(HIDDEN * LATENT + 255) / 256, 256, 0, stream>>>(W2, w2t_hi, w2t_lo, HIDDEN, LATENT);
    wsplit_kernel<<<(LATENT * HIDDEN + 255) / 256, 256, 0, stream>>>(Wd1, wd1t_hi, wd1t_lo, LATENT, HIDDEN);
    wsplit_kernel<<<(HIDDEN * IN_CH + 255) / 256, 256, 0, stream>>>(Wd2, wd2t_hi, wd2t_lo, HIDDEN, IN_CH);

    // AGGX: xa = D^-1/2 A^ D^-1/2 X (split out)
    aggx_kernel<<<(N + 3) / 4, 256, 0, stream>>>(xs, rowptr, col, dinv, xa_hi, xa_lo, N);

    const int mrows = (N + 127) / 128;  // 391

    // GEMM1: out1 = relu(xa @ W1 + b1) -> split   [N,128]x[128,256]
    gemm_bf16x3<128, 128, 2, 2, true, true, true, false>
        <<<dim3(mrows, HIDDEN / 128), 256, 0, stream>>>(
        xa_hi, xa_lo, w1t_hi, w1t_lo, nullptr, out1_hi, out1_lo, nullptr, b1, N, IN_CH, HIDDEN);
    // GEMM2: zs = (out1 @ W2) * dinv[row] -> fp32   [N,256]x[256,64]
    gemm_bf16x3<128, 64, 4, 1, false, false, false, true>
        <<<dim3(mrows, LATENT / 64), 256, 0, stream>>>(
        out1_hi, out1_lo, w2t_hi, w2t_lo, zs, nullptr, nullptr, dinv, nullptr, N, HIDDEN, LATENT);
    // AGG2: z = dinv*(sum) + b2 -> split
    agg64_kernel<<<(N + 3) / 4, 256, 0, stream>>>(zs, rowptr, col, dinv, b2, z_hi, z_lo, N);
    // GEMM3: d = relu(z @ Wd1 + bd1) -> split   [N,64]x[64,256]
    gemm_bf16x3<128, 128, 2, 2, true, true, true, false>
        <<<dim3(mrows, HIDDEN / 128), 256, 0, stream>>>(
        z_hi, z_lo, wd1t_hi, wd1t_lo, nullptr, d_hi, d_lo, nullptr, bd1, N, LATENT, HIDDEN);
    // GEMM4: out = d @ Wd2 + bd2 -> fp32   [N,256]x[256,128]
    gemm_bf16x3<128, 128, 2, 2, false, true, false, false>
        <<<dim3(mrows, IN_CH / 128), 256, 0, stream>>>(
        d_hi, d_lo, wd2t_hi, wd2t_lo, out, nullptr, nullptr, nullptr, bd2, N, HIDDEN, IN_CH);
}

// Round 6
// 395.544 us; speedup vs baseline: 1.3544x; 1.0040x over previous
//
#include <hip/hip_runtime.h>

// GraphAE: 2x GCNConv encoder + 2-layer MLP decoder.
// N=50000, IN=128, HID=256, LAT=64, E=800000. fp32 in/out.
//
// R6 changes vs R5:
//  - aggx: gather loop split into full-region (both slots valid) unrolled x4
//    with 4 independent accumulators -> ~4 outstanding row-gathers per wave.
//  - agg64: same, unrolled x2.
//  - GEMM4 uses BN=64 (782 blocks vs 391 -> kills the 1.5-block/CU tail).
// (R5: bf16x3 split-precision MFMA GEMMs, hi/lo planes produced by upstream
//  epilogues; weights pre-transposed+split. MFMA 16x16x32_bf16 layouts HW-
//  verified: A[m=lane&15][k=quad*8+j], B[k=..][n=lane&15], C/D col=lane&15,
//  row=quad*4+reg.)

#define IN_CH  128
#define HIDDEN 256
#define LATENT 64

typedef unsigned short u16;
typedef unsigned int u32;
typedef __bf16 bf16x8 __attribute__((ext_vector_type(8)));
typedef float f32x4 __attribute__((ext_vector_type(4)));

static __device__ __forceinline__ float4 ld4(const float* p) {
    return *reinterpret_cast<const float4*>(p);
}
static __device__ __forceinline__ void st4(float* p, float4 v) {
    *reinterpret_cast<float4*>(p) = v;
}
static __device__ __forceinline__ void acc4(float4& a, float4 v) {
    a.x += v.x; a.y += v.y; a.z += v.z; a.w += v.w;
}

// truncating hi/lo split: hi = top16(v); lo = top16(v - hi). v-hi is exact.
static __device__ __forceinline__ void split_bf16(float v, u16& hi, u16& lo) {
    u32 b = __float_as_uint(v);
    hi = (u16)(b >> 16);
    float hf = __uint_as_float(b & 0xFFFF0000u);
    lo = (u16)(__float_as_uint(v - hf) >> 16);
}

// ---------------- graph structure kernels ----------------

__global__ void hist_kernel(const int* __restrict__ ei, int E, int* __restrict__ counts) {
    int e = blockIdx.x * 256 + threadIdx.x;
    if (e < E) atomicAdd(&counts[ei[E + e]], 1);
}

__global__ void scan1_kernel(const int* __restrict__ counts, int* __restrict__ rowptr,
                             int* __restrict__ blocksums, int N) {
    __shared__ int sh[256];
    int tid = threadIdx.x;
    int i = blockIdx.x * 256 + tid;
    int v = (i < N) ? counts[i] : 0;
    sh[tid] = v;
    __syncthreads();
    for (int off = 1; off < 256; off <<= 1) {
        int t = (tid >= off) ? sh[tid - off] : 0;
        __syncthreads();
        sh[tid] += t;
        __syncthreads();
    }
    if (i < N) rowptr[i] = sh[tid] - v;
    if (tid == 255) blocksums[blockIdx.x] = sh[255];
}

__global__ void scan2_kernel(const int* __restrict__ blocksums, int* __restrict__ blockoffs,
                             int* __restrict__ rowptr, int nblk, int N) {
    __shared__ int sh[256];
    int tid = threadIdx.x;
    int v = (tid < nblk) ? blocksums[tid] : 0;
    sh[tid] = v;
    __syncthreads();
    for (int off = 1; off < 256; off <<= 1) {
        int t = (tid >= off) ? sh[tid - off] : 0;
        __syncthreads();
        sh[tid] += t;
        __syncthreads();
    }
    if (tid < nblk) blockoffs[tid] = sh[tid] - v;
    if (tid == nblk - 1) rowptr[N] = sh[tid];
}

__global__ void scan3_kernel(int* __restrict__ rowptr, const int* __restrict__ blockoffs,
                             int* __restrict__ next, int N) {
    int i = blockIdx.x * 256 + threadIdx.x;
    if (i < N) {
        int r = rowptr[i] + blockoffs[i >> 8];
        rowptr[i] = r;
        next[i] = r;
    }
}

__global__ void fill_kernel(const int* __restrict__ ei, int E,
                            int* __restrict__ next, int* __restrict__ col) {
    int e = blockIdx.x * 256 + threadIdx.x;
    if (e < E) {
        int s = ei[e];
        int d = ei[E + e];
        int pos = atomicAdd(&next[d], 1);
        col[pos] = s;
    }
}

__global__ void dinv_kernel(const int* __restrict__ counts, float* __restrict__ dinv, int N) {
    int i = blockIdx.x * 256 + threadIdx.x;
    if (i < N) dinv[i] = rsqrtf((float)counts[i] + 1.0f);
}

// xs[i,:] = dinv[i] * x[i,:]
__global__ void prescale_kernel(const float* __restrict__ x, const float* __restrict__ dinv,
                                float* __restrict__ xs, int total4) {
    int i = blockIdx.x * 256 + threadIdx.x;
    if (i < total4) {
        float s = dinv[i >> 5];
        float4 v = ld4(&x[(long)i * 4]);
        v.x *= s; v.y *= s; v.z *= s; v.w *= s;
        st4(&xs[(long)i * 4], v);
    }
}

// W[K,N] fp32 -> Wt_hi/Wt_lo [N,K] bf16 planes
__global__ void wsplit_kernel(const float* __restrict__ W, u16* __restrict__ Whi,
                              u16* __restrict__ Wlo, int K, int N) {
    int idx = blockIdx.x * 256 + threadIdx.x;
    if (idx < K * N) {
        int k = idx / N, n = idx % N;
        u16 h, l;
        split_bf16(W[idx], h, l);
        Whi[(long)n * K + k] = h;
        Wlo[(long)n * K + k] = l;
    }
}

// ---------------- bf16x3 MFMA GEMM ----------------

template <int BM, int BN, int WR, int WC, bool SPLIT_OUT, bool ADD_BIAS, bool RELU, bool SCALE_DINV>
__global__ __launch_bounds__(256) void gemm_bf16x3(
    const u16* __restrict__ Ahi, const u16* __restrict__ Alo,
    const u16* __restrict__ Bthi, const u16* __restrict__ Btlo,
    float* __restrict__ Cf, u16* __restrict__ Chi, u16* __restrict__ Clo,
    const float* __restrict__ dinv, const float* __restrict__ bias,
    int M, int K, int N) {
    constexpr int BK = 32;
    static_assert(WR * WC == 4, "4 waves");
    constexpr int MI = BM / (WR * 16);
    constexpr int NJ = BN / (WC * 16);
    constexpr int APER = BM * BK / 8 / 256;
    constexpr int BPER = BN * BK / 8 / 256;

    __shared__ u16 As[2][BM * BK];
    __shared__ u16 Bs[2][BN * BK];

    const int tid = threadIdx.x;
    const int wid = tid >> 6;
    const int lane = tid & 63;
    const int quad = lane >> 4;
    const int lm = lane & 15;
    const int wr = wid / WC;
    const int wc = wid % WC;
    const int row0 = blockIdx.x * BM;
    const int n0 = blockIdx.y * BN;

    f32x4 acc[MI][NJ];
#pragma unroll
    for (int i = 0; i < MI; i++)
#pragma unroll
        for (int j = 0; j < NJ; j++) acc[i][j] = (f32x4){0.f, 0.f, 0.f, 0.f};

    for (int k0 = 0; k0 < K; k0 += BK) {
#pragma unroll
        for (int t = 0; t < APER; t++) {
            int idx = tid + t * 256;
            int m = idx >> 2;
            int kg = (idx & 3) * 8;
            int row = row0 + m;
            uint4 vh = make_uint4(0, 0, 0, 0), vl = make_uint4(0, 0, 0, 0);
            if (row < M) {
                vh = *(const uint4*)&Ahi[(long)row * K + k0 + kg];
                vl = *(const uint4*)&Alo[(long)row * K + k0 + kg];
            }
            *(uint4*)&As[0][m * BK + kg] = vh;
            *(uint4*)&As[1][m * BK + kg] = vl;
        }
#pragma unroll
        for (int t = 0; t < BPER; t++) {
            int idx = tid + t * 256;
            int n = idx >> 2;
            int kg = (idx & 3) * 8;
            *(uint4*)&Bs[0][n * BK + kg] = *(const uint4*)&Bthi[(long)(n0 + n) * K + k0 + kg];
            *(uint4*)&Bs[1][n * BK + kg] = *(const uint4*)&Btlo[(long)(n0 + n) * K + k0 + kg];
        }
        __syncthreads();

        bf16x8 ah[MI], al[MI], bh[NJ], bl[NJ];
#pragma unroll
        for (int i = 0; i < MI; i++) {
            int m = wr * (MI * 16) + i * 16 + lm;
            ah[i] = *(const bf16x8*)&As[0][m * BK + quad * 8];
            al[i] = *(const bf16x8*)&As[1][m * BK + quad * 8];
        }
#pragma unroll
        for (int j = 0; j < NJ; j++) {
            int n = wc * (NJ * 16) + j * 16 + lm;
            bh[j] = *(const bf16x8*)&Bs[0][n * BK + quad * 8];
            bl[j] = *(const bf16x8*)&Bs[1][n * BK + quad * 8];
        }
#pragma unroll
        for (int i = 0; i < MI; i++)
#pragma unroll
            for (int j = 0; j < NJ; j++) {
                acc[i][j] = __builtin_amdgcn_mfma_f32_16x16x32_bf16(ah[i], bh[j], acc[i][j], 0, 0, 0);
                acc[i][j] = __builtin_amdgcn_mfma_f32_16x16x32_bf16(ah[i], bl[j], acc[i][j], 0, 0, 0);
                acc[i][j] = __builtin_amdgcn_mfma_f32_16x16x32_bf16(al[i], bh[j], acc[i][j], 0, 0, 0);
            }
        __syncthreads();
    }

#pragma unroll
    for (int i = 0; i < MI; i++)
#pragma unroll
        for (int j = 0; j < NJ; j++) {
            int coln = n0 + wc * (NJ * 16) + j * 16 + lm;
            float bi = ADD_BIAS ? bias[coln] : 0.0f;
#pragma unroll
            for (int r = 0; r < 4; r++) {
                int row = row0 + wr * (MI * 16) + i * 16 + quad * 4 + r;
                if (row < M) {
                    float v = acc[i][j][r];
                    if (SCALE_DINV) v *= dinv[row];
                    if (ADD_BIAS) v += bi;
                    if (RELU) v = fmaxf(v, 0.f);
                    if (SPLIT_OUT) {
                        u16 h, l;
                        split_bf16(v, h, l);
                        Chi[(long)row * N + coln] = h;
                        Clo[(long)row * N + coln] = l;
                    } else {
                        Cf[(long)row * N + coln] = v;
                    }
                }
            }
        }
}

// ---------------- aggregation kernels ----------------

// AGGX: xa[i] = dinv[i]*(xs[i] + sum_in xs[s]); writes SPLIT hi/lo planes.
// One wave per node, 2 slots x 32 lanes x float4. Full region (both slots
// valid) unrolled x4 with 4 accumulators -> 4 outstanding gathers/wave.
__global__ __launch_bounds__(256) void aggx_kernel(
    const float* __restrict__ xs, const int* __restrict__ rowptr, const int* __restrict__ col,
    const float* __restrict__ dinv, u16* __restrict__ xahi, u16* __restrict__ xalo, int N) {
    int wid = threadIdx.x >> 6;
    int lane = threadIdx.x & 63;
    int node = blockIdx.x * 4 + wid;
    if (node >= N) return;
    int slot = lane >> 5;
    int c = (lane & 31) * 4;

    float4 a0 = make_float4(0.f, 0.f, 0.f, 0.f);
    float4 a1 = a0, a2 = a0, a3 = a0;
    if (slot == 0) a0 = ld4(&xs[(long)node * 128 + c]);  // self term

    int beg = rowptr[node];
    int end = rowptr[node + 1];
    for (int cb = beg; cb < end; cb += 64) {
        int cnt = min(64, end - cb);
        int cv = (lane < cnt) ? col[cb + lane] : 0;
        int full = cnt >> 1;            // trips where both slots valid
        int trips = (cnt + 1) >> 1;
        int t = 0;
        for (; t + 4 <= full; t += 4) {
            int j = slot + 2 * t;
            int s0 = __shfl(cv, j);
            int s1 = __shfl(cv, j + 2);
            int s2 = __shfl(cv, j + 4);
            int s3 = __shfl(cv, j + 6);
            float4 v0 = ld4(&xs[(long)s0 * 128 + c]);
            float4 v1 = ld4(&xs[(long)s1 * 128 + c]);
            float4 v2 = ld4(&xs[(long)s2 * 128 + c]);
            float4 v3 = ld4(&xs[(long)s3 * 128 + c]);
            acc4(a0, v0); acc4(a1, v1); acc4(a2, v2); acc4(a3, v3);
        }
        for (; t < trips; t++) {
            int j = slot + 2 * t;
            bool p = j < cnt;
            int s = __shfl(cv, p ? j : 0);
            if (p) acc4(a0, ld4(&xs[(long)s * 128 + c]));
        }
    }
    acc4(a0, a1); acc4(a2, a3); acc4(a0, a2);
    a0.x += __shfl_xor(a0.x, 32);
    a0.y += __shfl_xor(a0.y, 32);
    a0.z += __shfl_xor(a0.z, 32);
    a0.w += __shfl_xor(a0.w, 32);
    if (slot == 0) {
        float di = dinv[node];
        a0.x *= di; a0.y *= di; a0.z *= di; a0.w *= di;
        ushort4 h, l;
        split_bf16(a0.x, h.x, l.x);
        split_bf16(a0.y, h.y, l.y);
        split_bf16(a0.z, h.z, l.z);
        split_bf16(a0.w, h.w, l.w);
        *(ushort4*)&xahi[(long)node * 128 + c] = h;
        *(ushort4*)&xalo[(long)node * 128 + c] = l;
    }
}

// AGG2: z[i] = dinv[i]*(zs[i] + sum_in zs[s]) + b2; writes SPLIT hi/lo planes.
// One wave per node, 4 slots x 16 lanes x float4; full region unrolled x2.
__global__ __launch_bounds__(256) void agg64_kernel(
    const float* __restrict__ zs, const int* __restrict__ rowptr, const int* __restrict__ col,
    const float* __restrict__ dinv, const float* __restrict__ bias,
    u16* __restrict__ zhi, u16* __restrict__ zlo, int N) {
    int wid = threadIdx.x >> 6;
    int lane = threadIdx.x & 63;
    int node = blockIdx.x * 4 + wid;
    if (node >= N) return;
    int slot = lane >> 4;
    int c = (lane & 15) * 4;

    float4 a0 = make_float4(0.f, 0.f, 0.f, 0.f);
    float4 a1 = a0;
    if (slot == 0) a0 = ld4(&zs[(long)node * 64 + c]);  // self term

    int beg = rowptr[node];
    int end = rowptr[node + 1];
    for (int cb = beg; cb < end; cb += 64) {
        int cnt = min(64, end - cb);
        int cv = (lane < cnt) ? col[cb + lane] : 0;
        int full = cnt >> 2;            // trips where all 4 slots valid
        int trips = (cnt + 3) >> 2;
        int t = 0;
        for (; t + 2 <= full; t += 2) {
            int j = slot + 4 * t;
            int s0 = __shfl(cv, j);
            int s1 = __shfl(cv, j + 4);
            float4 v0 = ld4(&zs[(long)s0 * 64 + c]);
            float4 v1 = ld4(&zs[(long)s1 * 64 + c]);
            acc4(a0, v0); acc4(a1, v1);
        }
        for (; t < trips; t++) {
            int j = slot + 4 * t;
            bool p = j < cnt;
            int s = __shfl(cv, p ? j : 0);
            if (p) acc4(a0, ld4(&zs[(long)s * 64 + c]));
        }
    }
    acc4(a0, a1);
    a0.x += __shfl_xor(a0.x, 16); a0.x += __shfl_xor(a0.x, 32);
    a0.y += __shfl_xor(a0.y, 16); a0.y += __shfl_xor(a0.y, 32);
    a0.z += __shfl_xor(a0.z, 16); a0.z += __shfl_xor(a0.z, 32);
    a0.w += __shfl_xor(a0.w, 16); a0.w += __shfl_xor(a0.w, 32);
    if (slot == 0) {
        float di = dinv[node];
        float4 bi = ld4(&bias[c]);
        a0.x = a0.x * di + bi.x;
        a0.y = a0.y * di + bi.y;
        a0.z = a0.z * di + bi.z;
        a0.w = a0.w * di + bi.w;
        ushort4 h, l;
        split_bf16(a0.x, h.x, l.x);
        split_bf16(a0.y, h.y, l.y);
        split_bf16(a0.z, h.z, l.z);
        split_bf16(a0.w, h.w, l.w);
        *(ushort4*)&zhi[(long)node * 64 + c] = h;
        *(ushort4*)&zlo[(long)node * 64 + c] = l;
    }
}

// ---------------- launch ----------------

extern "C" void kernel_launch(void* const* d_in, const int* in_sizes, int n_in,
                              void* d_out, int out_size, void* d_ws, size_t ws_size,
                              hipStream_t stream) {
    const float* x        = (const float*)d_in[0];
    const int* ei         = (const int*)d_in[1];   // int32 (harness integer convention)
    const float* W1       = (const float*)d_in[2];
    const float* b1       = (const float*)d_in[3];
    const float* W2       = (const float*)d_in[4];
    const float* b2       = (const float*)d_in[5];
    const float* Wd1      = (const float*)d_in[6];
    const float* bd1      = (const float*)d_in[7];
    const float* Wd2      = (const float*)d_in[8];
    const float* bd2      = (const float*)d_in[9];
    float* out            = (float*)d_out;

    const int N = in_sizes[0] / IN_CH;   // 50000
    const int E = in_sizes[1] / 2;       // 800000

    char* p = (char*)d_ws;
    auto alloc = [&](size_t bytes) {
        char* r = p;
        p += (bytes + 255) & ~(size_t)255;
        return r;
    };
    int*   counts    = (int*)  alloc((size_t)(N + 1) * 4);
    int*   rowptr    = (int*)  alloc((size_t)(N + 1) * 4);
    int*   nxt       = (int*)  alloc((size_t)N * 4);
    int*   blocksums = (int*)  alloc(256 * 4);
    int*   blockoffs = (int*)  alloc(256 * 4);
    float* dinv      = (float*)alloc((size_t)N * 4);
    int*   col       = (int*)  alloc((size_t)E * 4);
    float* xs        = (float*)alloc((size_t)N * IN_CH * 4);      // fp32; reused as d_hi
    u16*   blk2      = (u16*)  alloc((size_t)N * HIDDEN * 2);     // xa_hi|xa_lo; reused as d_lo
    u16*   out1_hi   = (u16*)  alloc((size_t)N * HIDDEN * 2);
    u16*   out1_lo   = (u16*)  alloc((size_t)N * HIDDEN * 2);
    float* zs        = (float*)alloc((size_t)N * LATENT * 4);
    u16*   z_hi      = (u16*)  alloc((size_t)N * LATENT * 2);
    u16*   z_lo      = (u16*)  alloc((size_t)N * LATENT * 2);
    u16*   w1t_hi    = (u16*)  alloc((size_t)IN_CH * HIDDEN * 2);
    u16*   w1t_lo    = (u16*)  alloc((size_t)IN_CH * HIDDEN * 2);
    u16*   w2t_hi    = (u16*)  alloc((size_t)HIDDEN * LATENT * 2);
    u16*   w2t_lo    = (u16*)  alloc((size_t)HIDDEN * LATENT * 2);
    u16*   wd1t_hi   = (u16*)  alloc((size_t)LATENT * HIDDEN * 2);
    u16*   wd1t_lo   = (u16*)  alloc((size_t)LATENT * HIDDEN * 2);
    u16*   wd2t_hi   = (u16*)  alloc((size_t)HIDDEN * IN_CH * 2);
    u16*   wd2t_lo   = (u16*)  alloc((size_t)HIDDEN * IN_CH * 2);

    u16* xa_hi = blk2;
    u16* xa_lo = blk2 + (size_t)N * IN_CH;
    u16* d_hi = (u16*)xs;   // xs dead after aggx
    u16* d_lo = blk2;       // xa dead after GEMM1

    const int nblk = (N + 255) / 256;

    hipMemsetAsync(counts, 0, (size_t)(N + 1) * 4, stream);
    hist_kernel<<<(E + 255) / 256, 256, 0, stream>>>(ei, E, counts);
    scan1_kernel<<<nblk, 256, 0, stream>>>(counts, rowptr, blocksums, N);
    scan2_kernel<<<1, 256, 0, stream>>>(blocksums, blockoffs, rowptr, nblk, N);
    scan3_kernel<<<nblk, 256, 0, stream>>>(rowptr, blockoffs, nxt, N);
    fill_kernel<<<(E + 255) / 256, 256, 0, stream>>>(ei, E, nxt, col);
    dinv_kernel<<<nblk, 256, 0, stream>>>(counts, dinv, N);

    const int total4 = N * (IN_CH / 4);
    prescale_kernel<<<(total4 + 255) / 256, 256, 0, stream>>>(x, dinv, xs, total4);

    wsplit_kernel<<<(IN_CH * HIDDEN + 255) / 256, 256, 0, stream>>>(W1, w1t_hi, w1t_lo, IN_CH, HIDDEN);
    wsplit_kernel<<<(HIDDEN * LATENT + 255) / 256, 256, 0, stream>>>(W2, w2t_hi, w2t_lo, HIDDEN, LATENT);
    wsplit_kernel<<<(LATENT * HIDDEN + 255) / 256, 256, 0, stream>>>(Wd1, wd1t_hi, wd1t_lo, LATENT, HIDDEN);
    wsplit_kernel<<<(HIDDEN * IN_CH + 255) / 256, 256, 0, stream>>>(Wd2, wd2t_hi, wd2t_lo, HIDDEN, IN_CH);

    // AGGX: xa = D^-1/2 A^ D^-1/2 X (split out)
    aggx_kernel<<<(N + 3) / 4, 256, 0, stream>>>(xs, rowptr, col, dinv, xa_hi, xa_lo, N);

    const int mrows = (N + 127) / 128;  // 391

    // GEMM1: out1 = relu(xa @ W1 + b1) -> split   [N,128]x[128,256]
    gemm_bf16x3<128, 128, 2, 2, true, true, true, false>
        <<<dim3(mrows, HIDDEN / 128), 256, 0, stream>>>(
        xa_hi, xa_lo, w1t_hi, w1t_lo, nullptr, out1_hi, out1_lo, nullptr, b1, N, IN_CH, HIDDEN);
    // GEMM2: zs = (out1 @ W2) * dinv[row] -> fp32   [N,256]x[256,64]
    gemm_bf16x3<128, 64, 4, 1, false, false, false, true>
        <<<dim3(mrows, LATENT / 64), 256, 0, stream>>>(
        out1_hi, out1_lo, w2t_hi, w2t_lo, zs, nullptr, nullptr, dinv, nullptr, N, HIDDEN, LATENT);
    // AGG2: z = dinv*(sum) + b2 -> split
    agg64_kernel<<<(N + 3) / 4, 256, 0, stream>>>(zs, rowptr, col, dinv, b2, z_hi, z_lo, N);
    // GEMM3: d = relu(z @ Wd1 + bd1) -> split   [N,64]x[64,256]
    gemm_bf16x3<128, 128, 2, 2, true, true, true, false>
        <<<dim3(mrows, HIDDEN / 128), 256, 0, stream>>>(
        z_hi, z_lo, wd1t_hi, wd1t_lo, nullptr, d_hi, d_lo, nullptr, bd1, N, LATENT, HIDDEN);
    // GEMM4: out = d @ Wd2 + bd2 -> fp32   [N,256]x[256,128]  (BN=64: 782 blocks)
    gemm_bf16x3<128, 64, 4, 1, false, true, false, false>
        <<<dim3(mrows, IN_CH / 64), 256, 0, stream>>>(
        d_hi, d_lo, wd2t_hi, wd2t_lo, out, nullptr, nullptr, nullptr, bd2, N, HIDDEN, IN_CH);
}